// Round 7
// baseline (85.733 us; speedup 1.0000x reference)
//
#include <hip/hip_runtime.h>

#define DD 256
#define DD2 (DD * DD)
#define DD3 (DD * DD * DD)
#define TH 20    // sponge thickness
#define XSEG 8   // x-planes marched per block

typedef float f32x4 __attribute__((ext_vector_type(4)));

__device__ __forceinline__ f32x4 ld4_sum(const float* __restrict__ p,
                                         const float* __restrict__ s,
                                         int idx) {
    return *reinterpret_cast<const f32x4*>(p + idx) +
           *reinterpret_cast<const f32x4*>(s + idx);
}

__device__ __forceinline__ f32x4 rcp4(f32x4 x) {
    f32x4 r;
    r.x = __builtin_amdgcn_rcpf(x.x);
    r.y = __builtin_amdgcn_rcpf(x.y);
    r.z = __builtin_amdgcn_rcpf(x.z);
    r.w = __builtin_amdgcn_rcpf(x.w);
    return r;
}

// Block = 4 waves; wave = one z-line (64 lanes x float4) x 4 y-rows.
// Each block MARCHES along x over XSEG planes, keeping three 6-row u-columns
// (x-1, x, x+1) in registers: per step only the new x+1 column is loaded.
// Cache-tier pc+src bytes/output: 112 -> 48. pp/aa stream NT; sigma loaded
// only where the 20-cell sponge shell is touchable (exactly 0 elsewhere).
__global__ __launch_bounds__(256) void sponge_kernel(
    const float* __restrict__ src,
    const float* __restrict__ pc,
    const float* __restrict__ pp,
    const float* __restrict__ aa,
    const float* __restrict__ sg,
    const float* __restrict__ dtp,
    float* __restrict__ out_pnew,
    float* __restrict__ out_pcur)
{
    const float dt = dtp[0];

    const int lane = threadIdx.x & 63;        // z = lane*4
    const int w    = threadIdx.x >> 6;        // wave 0..3

    // 512 blocks; bijective XCD swizzle (64 per XCD). ytile inner so each
    // XCD owns 4 contiguous x-segments (32-plane slab) across all y.
    const int wid   = (blockIdx.x & 7) * 64 + (blockIdx.x >> 3);
    const int ytile = wid & 15;                // 0..15
    const int xseg  = wid >> 4;                // 0..31
    const int y0    = ytile * 16 + w * 4;      // rows y0..y0+3
    const int x0    = xseg * XSEG;
    const int basez = lane * 4;

    const bool zsp = (lane < TH / 4) | (lane >= (DD - TH + 3) / 4);

    f32x4 colA[6], colB[6], colC[6];           // u columns at x-1, x, x+1

    // ---- prologue: columns at x0-1 and x0 ----
#pragma unroll
    for (int r = 0; r < 6; ++r) {
        const int yy = y0 - 1 + r;
        colA[r] = (f32x4)(0.0f);
        colB[r] = (f32x4)(0.0f);
        if (yy >= 0 && yy < DD) {
            if (x0 > 0) colA[r] = ld4_sum(pc, src, (x0 - 1) * DD2 + yy * DD + basez);
            colB[r] = ld4_sum(pc, src, x0 * DD2 + yy * DD + basez);
        }
    }

#pragma unroll
    for (int st = 0; st < XSEG; ++st) {
        const int x  = x0 + st;
        const int pb = x * DD2 + basez;

        // 1) single-touch HBM streams first (longest latency, NT)
        f32x4 p4v[4], a4v[4];
#pragma unroll
        for (int r = 0; r < 4; ++r) {
            const int idx = pb + (y0 + r) * DD;
            p4v[r] = __builtin_nontemporal_load(reinterpret_cast<const f32x4*>(pp + idx));
            a4v[r] = __builtin_nontemporal_load(reinterpret_cast<const f32x4*>(aa + idx));
        }

        // 2) sigma: exactly 0 outside the sponge shell
        const bool xsp = (x < TH) | (x >= DD - TH);
        f32x4 s4v[4];
#pragma unroll
        for (int r = 0; r < 4; ++r) {
            const int yy = y0 + r;
            const bool sp = xsp | zsp | (yy < TH) | (yy >= DD - TH);
            s4v[r] = sp ? *reinterpret_cast<const f32x4*>(sg + pb + yy * DD)
                        : (f32x4)(0.0f);
        }

        // 3) new column at x+1 (only fresh cache-tier loads of the step)
#pragma unroll
        for (int r = 0; r < 6; ++r) {
            const int yy = y0 - 1 + r;
            colC[r] = (f32x4)(0.0f);
            if (x < DD - 1 && yy >= 0 && yy < DD)
                colC[r] = ld4_sum(pc, src, (x + 1) * DD2 + yy * DD + basez);
        }

        // 4) compute + store 4 rows
#pragma unroll
        for (int r = 0; r < 4; ++r) {
            const int idx = pb + (y0 + r) * DD;
            const f32x4 u = colB[r + 1];

            // z neighbors via cross-lane shuffle; lane edges == grid z faces
            float left  = __shfl_up(u.w, 1);
            float right = __shfl_down(u.x, 1);
            if (lane == 0)  left  = 0.0f;
            if (lane == 63) right = 0.0f;

            f32x4 lap;
            lap.x = left  + u.y + colB[r].x + colB[r + 2].x + colA[r + 1].x + colC[r + 1].x - 6.0f * u.x;
            lap.y = u.x   + u.z + colB[r].y + colB[r + 2].y + colA[r + 1].y + colC[r + 1].y - 6.0f * u.y;
            lap.z = u.y   + u.w + colB[r].z + colB[r + 2].z + colA[r + 1].z + colC[r + 1].z - 6.0f * u.z;
            lap.w = u.z   + right + colB[r].w + colB[r + 2].w + colA[r + 1].w + colC[r + 1].w - 6.0f * u.w;

            const f32x4 half = (0.5f * dt) * s4v[r];
            const f32x4 num  = 2.0f * u - (1.0f - half) * p4v[r] + a4v[r] * lap;
            const f32x4 pn   = num * rcp4(1.0f + half);

            __builtin_nontemporal_store(pn, reinterpret_cast<f32x4*>(out_pnew + idx));
            __builtin_nontemporal_store(u,  reinterpret_cast<f32x4*>(out_pcur + idx));
        }

        // 5) rotate columns (static indices; unrolled copies -> renamed regs)
#pragma unroll
        for (int r = 0; r < 6; ++r) {
            colA[r] = colB[r];
            colB[r] = colC[r];
        }
    }
}

extern "C" void kernel_launch(void* const* d_in, const int* in_sizes, int n_in,
                              void* d_out, int out_size, void* d_ws, size_t ws_size,
                              hipStream_t stream) {
    const float* src = (const float*)d_in[0];
    const float* pc  = (const float*)d_in[1];
    const float* pp  = (const float*)d_in[2];
    const float* aa  = (const float*)d_in[3];
    const float* sg  = (const float*)d_in[4];
    const float* dtp = (const float*)d_in[5];
    float* out = (float*)d_out;

    // 16 y-tiles x 32 x-segments = 512 blocks (divisible by 8)
    const int grid = 16 * (DD / XSEG);
    sponge_kernel<<<grid, 256, 0, stream>>>(src, pc, pp, aa, sg, dtp,
                                            out, out + DD3);
}